// Round 16
// baseline (1715.618 us; speedup 1.0000x reference)
//
#include <hip/hip_runtime.h>
#include <cstdint>

#define N_PTS 100000
#define N_EDGE 800000
#define N_ITEMS (N_EDGE + N_PTS)   // real edges + self-loops
#define IMG_W 1216
#define IMG_H 240
#define OW 304
#define OH 60
#define CHUNK 32
#define BIN_BLOCKS 391   // ceil(N_PTS/256)

typedef _Float16 f16;
typedef _Float16 f16x8 __attribute__((ext_vector_type(8)));
typedef float f32x4 __attribute__((ext_vector_type(4)));

__device__ __forceinline__ void atomicMaxF(float* addr, float v) {
    // float max via int max (v>=0) / uint min (v<0); exact, order-independent.
    if (v >= 0.0f) atomicMax((int*)addr, __float_as_int(v));
    else atomicMin((unsigned int*)addr, __float_as_uint(v));
}

// ---------------- init OUT to -inf ----------------
__global__ __launch_bounds__(256)
void init_out_kernel(float* __restrict__ p, long n)   // n multiple of 4
{
    long i = ((long)blockIdx.x * 256 + threadIdx.x) * 4;
    if (i < n) {
        float4 v = {-INFINITY, -INFINITY, -INFINITY, -INFINITY};
        *(float4*)&p[i] = v;
    }
}

// ---------------- MFMA node kernel: A[n] = [X|pos]@w1 + b1 (f16) ----------------
template<int DX, int KP, int D>
__global__ __launch_bounds__(256)
void node_mfma_kernel(const float* __restrict__ X, const float* __restrict__ pos,
                      const f16* __restrict__ w1t, const float* __restrict__ b1,
                      f16* __restrict__ A)
{
    constexpr int KB = KP / 32;
    constexpr int NB = D / 16;
    const int tid = threadIdx.x;
    const int wave = tid >> 6;
    const int lane = tid & 63;
    const int row = lane & 15;
    const int kg = lane >> 4;
    const int wbase = (blockIdx.x * 4 + wave) * 32;

    f16x8 pa[2][KB];
#pragma unroll
    for (int mh = 0; mh < 2; ++mh) {
        int n = wbase + mh * 16 + row;
        int ns = (n < N_PTS) ? n : 0;
#pragma unroll
        for (int kb = 0; kb < KB; ++kb) {
            const int c0 = kb * 32 + kg * 8;
            f16x8 h;
#pragma unroll
            for (int j = 0; j < 8; ++j) {
                int k = c0 + j;
                float v = 0.0f;
                if (k < DX) v = X[(long)ns * DX + k];
                else if (k < DX + 3) v = pos[(long)ns * 3 + (k - DX)];
                h[j] = (f16)v;
            }
            pa[mh][kb] = h;
        }
    }

#pragma unroll 2
    for (int nb = 0; nb < NB; ++nb) {
        f32x4 acc0 = {0.0f, 0.0f, 0.0f, 0.0f};
        f32x4 acc1 = {0.0f, 0.0f, 0.0f, 0.0f};
#pragma unroll
        for (int kb = 0; kb < KB; ++kb) {
            f16x8 pb = *(const f16x8*)&w1t[(long)(nb * 16 + row) * KP + kb * 32 + kg * 8];
            acc0 = __builtin_amdgcn_mfma_f32_16x16x32_f16(pa[0][kb], pb, acc0, 0, 0, 0);
            acc1 = __builtin_amdgcn_mfma_f32_16x16x32_f16(pa[1][kb], pb, acc1, 0, 0, 0);
        }
        const int col = nb * 16 + row;
        const float bb = b1[col];
#pragma unroll
        for (int reg = 0; reg < 4; ++reg) {
            int r = kg * 4 + reg;
            int n0 = wbase + r;
            int n1 = wbase + 16 + r;
            if (n0 < N_PTS) A[(long)n0 * D + col] = (f16)(acc0[reg] + bb);
            if (n1 < N_PTS) A[(long)n1 * D + col] = (f16)(acc1[reg] + bb);
        }
    }
}

// ---------------- weight prep ----------------
__global__ void cvt_w1(const float* __restrict__ w1, f16* __restrict__ w1t,
                       int K, int KP, int D)
{
    int i = blockIdx.x * 256 + threadIdx.x;
    if (i >= D * KP) return;
    int c = i / KP, k = i % KP;
    w1t[i] = (k < K) ? (f16)w1[k * D + c] : (f16)0.0f;
}

__global__ void cvt_w2(const float* __restrict__ w2, f16* __restrict__ w2t, int D)
{
    int i = blockIdx.x * 256 + threadIdx.x;
    if (i >= D * D) return;
    int n = i / D, k = i % D;
    w2t[i] = (f16)w2[k * D + n];
}

// ---------------- counting sort of (edges + self-loops) by dst ----------------
__global__ void init_hist_kernel(int* __restrict__ hist)
{
    int i = blockIdx.x * 256 + threadIdx.x;
    if (i < N_PTS) hist[i] = 1;   // self-loop
}

__global__ void hist_kernel(const int* __restrict__ ei, int* __restrict__ hist)
{
    int e = blockIdx.x * 256 + threadIdx.x;
    if (e < N_EDGE) atomicAdd(&hist[ei[N_EDGE + e]], 1);
}

__global__ void bsum_kernel(const int* __restrict__ hist, int* __restrict__ bsum)
{
    __shared__ int s[256];
    int i = blockIdx.x * 256 + threadIdx.x;
    s[threadIdx.x] = (i < N_PTS) ? hist[i] : 0;
    __syncthreads();
    for (int off = 128; off > 0; off >>= 1) {
        if (threadIdx.x < off) s[threadIdx.x] += s[threadIdx.x + off];
        __syncthreads();
    }
    if (threadIdx.x == 0) bsum[blockIdx.x] = s[0];
}

__global__ void scan_bsum_kernel(int* __restrict__ bsum)
{
    __shared__ int s[512];
    int t = threadIdx.x;
    int v = (t < BIN_BLOCKS) ? bsum[t] : 0;
    s[t] = v;
    __syncthreads();
    for (int off = 1; off < 512; off <<= 1) {
        int u = (t >= off) ? s[t - off] : 0;
        __syncthreads();
        s[t] += u;
        __syncthreads();
    }
    if (t < BIN_BLOCKS) bsum[t] = s[t] - v;   // exclusive
}

__global__ void rowptr_kernel(const int* __restrict__ hist, const int* __restrict__ bsum,
                              int* __restrict__ woff)
{
    __shared__ int s[256];
    int i = blockIdx.x * 256 + threadIdx.x;
    int v = (i < N_PTS) ? hist[i] : 0;
    s[threadIdx.x] = v;
    __syncthreads();
    for (int off = 1; off < 256; off <<= 1) {
        int u = (threadIdx.x >= off) ? s[threadIdx.x - off] : 0;
        __syncthreads();
        s[threadIdx.x] += u;
        __syncthreads();
    }
    if (i < N_PTS) woff[i] = bsum[blockIdx.x] + s[threadIdx.x] - v;  // exclusive
}

__global__ void scatter_edges_kernel(const int* __restrict__ ei, int* __restrict__ woff,
                                     int* __restrict__ srcS, int* __restrict__ dstS)
{
    int e = blockIdx.x * 256 + threadIdx.x;
    if (e >= N_ITEMS) return;
    int s, d;
    if (e < N_EDGE) { s = ei[e]; d = ei[N_EDGE + e]; }
    else            { s = d = e - N_EDGE; }
    int p = atomicAdd(&woff[d], 1);
    srcS[p] = s;
    dstS[p] = d;
}

// ---------------- persistent 32-item MFMA message kernel (XKG dedup) D=64/128 -------
template<int D>
__global__ __launch_bounds__(256)
void gemm_msg_kernel(const int* __restrict__ srcA, const int* __restrict__ dstA,
                     const f16* __restrict__ A, const float* __restrict__ pos,
                     const float* __restrict__ w1p, const f16* __restrict__ w2t,
                     const float* __restrict__ b2, float* __restrict__ OUT, int nItems)
{
    constexpr int KB = D / 32;
    constexpr int NB = D / 16;
    const int tid = threadIdx.x;
    const int wave = tid >> 6;
    const int lane = tid & 63;
    const int row = lane & 15;
    const int kg = lane >> 4;
    const int nWin = (nItems + 31) >> 5;

    for (int win = blockIdx.x * 4 + wave; win < nWin; win += gridDim.x * 4) {
        const long wbase = (long)win * 32;
        int zero = 0;
        asm volatile("" : "+v"(zero));          // opaque 0: blocks cross-iter load hoisting
        const f16* w2tp = w2t + zero;

        int s[2], d[2];
        float px[2], py[2], pz[2];
#pragma unroll
        for (int mh = 0; mh < 2; ++mh) {
            long e = wbase + mh * 16 + row;
            bool ok = (e < nItems);
            int ss = ok ? srcA[e] : 0;
            int dd = ok ? dstA[e] : -1;
            s[mh] = ss; d[mh] = dd;
            int dsafe = ok ? dd : 0;
            px[mh] = pos[(long)dsafe * 3 + 0];
            py[mh] = pos[(long)dsafe * 3 + 1];
            pz[mh] = pos[(long)dsafe * 3 + 2];
        }

        f16x8 pa[2][KB];
#pragma unroll
        for (int kb = 0; kb < KB; ++kb) {
            const int c0 = kb * 32 + kg * 8;
            f16x8 a0 = *(const f16x8*)&A[(long)s[0] * D + c0];
            f16x8 a1 = *(const f16x8*)&A[(long)s[1] * D + c0];
            f16x8 h0, h1;
#pragma unroll
            for (int j = 0; j < 8; ++j) {
                float wx = w1p[c0 + j];
                float wy = w1p[D + c0 + j];
                float wz = w1p[2 * D + c0 + j];
                h0[j] = (f16)fmaxf((float)a0[j] - (px[0] * wx + py[0] * wy + pz[0] * wz), 0.0f);
                h1[j] = (f16)fmaxf((float)a1[j] - (px[1] * wx + py[1] * wy + pz[1] * wz), 0.0f);
            }
            pa[0][kb] = h0;
            pa[1][kb] = h1;
        }

        int dd0[4], dd1[4];
#pragma unroll
        for (int reg = 0; reg < 4; ++reg) {
            int r = kg * 4 + reg;
            dd0[reg] = __shfl(d[0], r);
            dd1[reg] = __shfl(d[1], r);
        }
        const bool a01 = (dd0[1] == dd0[0]), a12 = (dd0[2] == dd0[1]), a23 = (dd0[3] == dd0[2]);
        const bool b01 = (dd1[1] == dd1[0]), b12 = (dd1[2] == dd1[1]), b23 = (dd1[3] == dd1[2]);
        const bool aAll = a01 && a12 && a23, bAll = b01 && b12 && b23;
        const int aN0 = __shfl(dd0[0], lane + 16);
        const int bN0 = __shfl(dd1[0], lane + 16);
        const int aFn = __shfl((int)aAll, lane + 16);
        const int bFn = __shfl((int)bAll, lane + 16);
        const bool aCo = (kg < 3) && (dd0[3] == aN0);
        const bool bCo = (kg < 3) && (dd1[3] == bN0);
        const int lprev = (lane >= 16) ? (lane - 16) : 0;
        const int aP3 = __shfl(dd0[3], lprev);
        const int bP3 = __shfl(dd1[3], lprev);
        const bool aHd = (kg == 0) || (dd0[0] != aP3);
        const bool bHd = (kg == 0) || (dd1[0] != bP3);

#pragma unroll
        for (int nb = 0; nb < NB; ++nb) {
            f32x4 acc0 = {0.0f, 0.0f, 0.0f, 0.0f};
            f32x4 acc1 = {0.0f, 0.0f, 0.0f, 0.0f};
#pragma unroll
            for (int kb = 0; kb < KB; ++kb) {
                f16x8 pb = *(const f16x8*)&w2tp[(long)(nb * 16 + row) * D + kb * 32 + kg * 8];
                acc0 = __builtin_amdgcn_mfma_f32_16x16x32_f16(pa[0][kb], pb, acc0, 0, 0, 0);
                acc1 = __builtin_amdgcn_mfma_f32_16x16x32_f16(pa[1][kb], pb, acc1, 0, 0, 0);
            }
            const int col = nb * 16 + row;
            const float bb = b2[col];
            {   // half 0
                const float v0 = acc0[0] + bb, v1 = acc0[1] + bb, v2 = acc0[2] + bb, v3 = acc0[3] + bb;
                const float s3 = v3;
                const float s2 = a23 ? fmaxf(v2, s3) : v2;
                const float s1 = a12 ? fmaxf(v1, s2) : v1;
                const float s0 = a01 ? fmaxf(v0, s1) : v0;
                float P = v0;
                P = a01 ? fmaxf(P, v1) : P;
                P = (a01 && a12) ? fmaxf(P, v2) : P;
                P = aAll ? fmaxf(P, v3) : P;
                float T = -INFINITY;
#pragma unroll
                for (int it = 0; it < 3; ++it) {
                    float Pn = __shfl(P, lane + 16);
                    float Tn = __shfl(T, lane + 16);
                    T = aCo ? fmaxf(Pn, aFn ? Tn : -INFINITY) : T;
                }
                const float x0 = aAll ? fmaxf(s0, T) : s0;
                const float x1 = (a12 && a23) ? fmaxf(s1, T) : s1;
                const float x2 = a23 ? fmaxf(s2, T) : s2;
                const float x3 = fmaxf(s3, T);
                if (aHd  && dd0[0] >= 0) atomicMaxF(&OUT[(long)dd0[0] * D + col], x0);
                if (!a01 && dd0[1] >= 0) atomicMaxF(&OUT[(long)dd0[1] * D + col], x1);
                if (!a12 && dd0[2] >= 0) atomicMaxF(&OUT[(long)dd0[2] * D + col], x2);
                if (!a23 && dd0[3] >= 0) atomicMaxF(&OUT[(long)dd0[3] * D + col], x3);
            }
            {   // half 1
                const float v0 = acc1[0] + bb, v1 = acc1[1] + bb, v2 = acc1[2] + bb, v3 = acc1[3] + bb;
                const float s3 = v3;
                const float s2 = b23 ? fmaxf(v2, s3) : v2;
                const float s1 = b12 ? fmaxf(v1, s2) : v1;
                const float s0 = b01 ? fmaxf(v0, s1) : v0;
                float P = v0;
                P = b01 ? fmaxf(P, v1) : P;
                P = (b01 && b12) ? fmaxf(P, v2) : P;
                P = bAll ? fmaxf(P, v3) : P;
                float T = -INFINITY;
#pragma unroll
                for (int it = 0; it < 3; ++it) {
                    float Pn = __shfl(P, lane + 16);
                    float Tn = __shfl(T, lane + 16);
                    T = bCo ? fmaxf(Pn, bFn ? Tn : -INFINITY) : T;
                }
                const float x0 = bAll ? fmaxf(s0, T) : s0;
                const float x1 = (b12 && b23) ? fmaxf(s1, T) : s1;
                const float x2 = b23 ? fmaxf(s2, T) : s2;
                const float x3 = fmaxf(s3, T);
                if (bHd  && dd1[0] >= 0) atomicMaxF(&OUT[(long)dd1[0] * D + col], x0);
                if (!b01 && dd1[1] >= 0) atomicMaxF(&OUT[(long)dd1[1] * D + col], x1);
                if (!b12 && dd1[2] >= 0) atomicMaxF(&OUT[(long)dd1[2] * D + col], x2);
                if (!b23 && dd1[3] >= 0) atomicMaxF(&OUT[(long)dd1[3] * D + col], x3);
            }
        }
    }
}

// ---------------- persistent standalone D=256 kernel (per-lane dedup, 128 VGPR) -----
__global__ __launch_bounds__(256)
void gemm_msg256_kernel(const int* __restrict__ srcA, const int* __restrict__ dstA,
                        const f16* __restrict__ A, const float* __restrict__ pos,
                        const float* __restrict__ w1p, const f16* __restrict__ w2t,
                        const float* __restrict__ b2, float* __restrict__ OUT, int nItems)
{
    const int tid = threadIdx.x;
    const int wave = tid >> 6;
    const int lane = tid & 63;
    const int row = lane & 15;
    const int kg = lane >> 4;
    const int nWin = (nItems + 31) >> 5;

    for (int win = blockIdx.x * 4 + wave; win < nWin; win += gridDim.x * 4) {
        const long wbase = (long)win * 32;
        int zero = 0;
        asm volatile("" : "+v"(zero));          // opaque 0: blocks cross-iter load hoisting
        const f16* w2tp = w2t + zero;

        int s[2], d[2];
        float px[2], py[2], pz[2];
#pragma unroll
        for (int mh = 0; mh < 2; ++mh) {
            long e = wbase + mh * 16 + row;
            bool ok = (e < nItems);
            int ss = ok ? srcA[e] : 0;
            int dd = ok ? dstA[e] : -1;
            s[mh] = ss; d[mh] = dd;
            int dsafe = ok ? dd : 0;
            px[mh] = pos[(long)dsafe * 3 + 0];
            py[mh] = pos[(long)dsafe * 3 + 1];
            pz[mh] = pos[(long)dsafe * 3 + 2];
        }

        f16x8 pa[2][8];
#pragma unroll
        for (int kb = 0; kb < 8; ++kb) {
            const int c0 = kb * 32 + kg * 8;
            f16x8 a0 = *(const f16x8*)&A[(long)s[0] * 256 + c0];
            f16x8 a1 = *(const f16x8*)&A[(long)s[1] * 256 + c0];
            f16x8 h0, h1;
#pragma unroll
            for (int j = 0; j < 8; ++j) {
                float wx = w1p[c0 + j];
                float wy = w1p[256 + c0 + j];
                float wz = w1p[512 + c0 + j];
                h0[j] = (f16)fmaxf((float)a0[j] - (px[0] * wx + py[0] * wy + pz[0] * wz), 0.0f);
                h1[j] = (f16)fmaxf((float)a1[j] - (px[1] * wx + py[1] * wy + pz[1] * wz), 0.0f);
            }
            pa[0][kb] = h0;
            pa[1][kb] = h1;
        }

        int dd0[4], dd1[4];
#pragma unroll
        for (int reg = 0; reg < 4; ++reg) {
            int r = kg * 4 + reg;
            dd0[reg] = __shfl(d[0], r);
            dd1[reg] = __shfl(d[1], r);
        }
        bool hd0[4], hd1[4];
        hd0[0] = true; hd1[0] = true;
#pragma unroll
        for (int reg = 1; reg < 4; ++reg) {
            hd0[reg] = (dd0[reg] != dd0[reg - 1]);
            hd1[reg] = (dd1[reg] != dd1[reg - 1]);
        }

#pragma unroll
        for (int nb = 0; nb < 16; ++nb) {
            f32x4 acc0 = {0.0f, 0.0f, 0.0f, 0.0f};
            f32x4 acc1 = {0.0f, 0.0f, 0.0f, 0.0f};
#pragma unroll
            for (int kb = 0; kb < 8; ++kb) {
                f16x8 pb = *(const f16x8*)&w2tp[(long)(nb * 16 + row) * 256 + kb * 32 + kg * 8];
                acc0 = __builtin_amdgcn_mfma_f32_16x16x32_f16(pa[0][kb], pb, acc0, 0, 0, 0);
                acc1 = __builtin_amdgcn_mfma_f32_16x16x32_f16(pa[1][kb], pb, acc1, 0, 0, 0);
            }
            const int col = nb * 16 + row;
            const float bb = b2[col];
            float v0[4], v1[4];
#pragma unroll
            for (int reg = 0; reg < 4; ++reg) { v0[reg] = acc0[reg] + bb; v1[reg] = acc1[reg] + bb; }
            float s0[4], s1[4];
            s0[3] = v0[3]; s1[3] = v1[3];
#pragma unroll
            for (int reg = 2; reg >= 0; --reg) {
                s0[reg] = hd0[reg + 1] ? v0[reg] : fmaxf(v0[reg], s0[reg + 1]);
                s1[reg] = hd1[reg + 1] ? v1[reg] : fmaxf(v1[reg], s1[reg + 1]);
            }
#pragma unroll
            for (int reg = 0; reg < 4; ++reg) {
                if (hd0[reg] && dd0[reg] >= 0) atomicMaxF(&OUT[(long)dd0[reg] * 256 + col], s0[reg]);
                if (hd1[reg] && dd1[reg] >= 0) atomicMaxF(&OUT[(long)dd1[reg] * 256 + col], s1[reg]);
            }
        }
    }
}

// ---------------- projection ----------------
__global__ void proj_kernel(const float* __restrict__ pos, const float* __restrict__ proj,
                            const int* __restrict__ img_h, const int* __restrict__ img_w,
                            int* __restrict__ pix)
{
    int n = blockIdx.x * blockDim.x + threadIdx.x;
    if (n >= N_PTS) return;
    float px = pos[n * 3 + 0], py = pos[n * 3 + 1], pz = pos[n * 3 + 2];
    float h0 = proj[0] * px + proj[1] * py + proj[2]  * pz + proj[3];
    float h1 = proj[4] * px + proj[5] * py + proj[6]  * pz + proj[7];
    float h2 = proj[8] * px + proj[9] * py + proj[10] * pz + proj[11];
    int off_u = img_w[0] - IMG_W;
    int off_v = img_h[0] - IMG_H;
    int ui = (int)(short)(h0 / h2) - off_u;   // int16 truncation semantics
    int vi = (int)(short)(h1 / h2) - off_v;
    bool valid = (ui >= 0) && (vi >= 0) && (ui < IMG_W) && (vi < IMG_H);
    pix[n] = valid ? (ui * IMG_H + vi) : -1;
}

// ---------------- scatter-add (pixel-major, CHUNK channels) ----------------
__global__ __launch_bounds__(256)
void scatter_kernel(const float* __restrict__ H, const int* __restrict__ pix,
                    float* __restrict__ img, int cbase)
{
    long g = (long)blockIdx.x * blockDim.x + threadIdx.x;
    if (g >= (long)N_PTS * CHUNK) return;
    int n = (int)(g / CHUNK);
    int c = (int)(g % CHUNK);
    int p = pix[n];
    if (p < 0) return;
    atomicAdd(&img[(long)p * CHUNK + c], H[(long)n * 256 + cbase + c]);
}

// ---------------- 4x4 max-pool ----------------
__global__ __launch_bounds__(CHUNK)
void pool_kernel(const float* __restrict__ img, float* __restrict__ out, int cbase)
{
    int cell = blockIdx.x;
    int wc = cell / OH, hc = cell % OH;
    int c = threadIdx.x;
    float mx = -INFINITY;
#pragma unroll
    for (int i = 0; i < 4; ++i)
#pragma unroll
        for (int j = 0; j < 4; ++j) {
            long p = (long)(wc * 4 + i) * IMG_H + (hc * 4 + j);
            mx = fmaxf(mx, img[p * CHUNK + c]);
        }
    out[(long)(cbase + c) * (OW * OH) + wc * OH + hc] = mx;
}

extern "C" void kernel_launch(void* const* d_in, const int* in_sizes, int n_in,
                              void* d_out, int out_size, void* d_ws, size_t ws_size,
                              hipStream_t stream)
{
    const float* x     = (const float*)d_in[0];
    const float* pos   = (const float*)d_in[1];
    const int*   ei    = (const int*)d_in[2];
    const float* proj  = (const float*)d_in[4];
    const int*   img_h = (const int*)d_in[5];
    const int*   img_w = (const int*)d_in[6];
    const float* w1_1 = (const float*)d_in[7];
    const float* b1_1 = (const float*)d_in[8];
    const float* w2_1 = (const float*)d_in[9];
    const float* b2_1 = (const float*)d_in[10];
    const float* w1_2 = (const float*)d_in[11];
    const float* b1_2 = (const float*)d_in[12];
    const float* w2_2 = (const float*)d_in[13];
    const float* b2_2 = (const float*)d_in[14];
    const float* w1_3 = (const float*)d_in[15];
    const float* b1_3 = (const float*)d_in[16];
    const float* w2_3 = (const float*)d_in[17];
    const float* b2_3 = (const float*)d_in[18];
    float* out = (float*)d_out;

    // ws layout (byte offsets), lifetime-aliased; peak = 162.4 MB (proven rounds 6-15)
    if (ws_size < 162400000ull) return;
    char* ws = (char*)d_ws;
    float* HH   = (float*)(ws + 0);
    float* F1   = (float*)(ws + 0);
    float* F0   = (float*)(ws + 51200000);
    f16*   A12  = (f16*)(ws + 76800000);
    f16*   A3   = (f16*)(ws + 102400000);
    float* img  = (float*)(ws + 102400000);
    int*   pix  = (int*)(ws + 153600000);
    f16*   w2t3 = (f16*)(ws + 154000000);
    f16*   w2t2 = (f16*)(ws + 154131072);
    f16*   w2t1 = (f16*)(ws + 154163840);
    int*   srcS = (int*)(ws + 154200000);
    int*   dstS = (int*)(ws + 157800000);
    int*   hist = (int*)(ws + 161400000);
    int*   woff = (int*)(ws + 161800000);
    int*   bsum = (int*)(ws + 162200000);
    f16*   w1t3 = (f16*)(ws + 162210000);
    f16*   w1t2 = (f16*)(ws + 162300000);
    f16*   w1t1 = (f16*)(ws + 162330000);

    const int NODE_BLOCKS = (N_PTS + 127) / 128;    // 782 (4 waves x 32 rows)
    const int EDGE_P_BLOCKS = 1024;                 // persistent grid-stride
    const int E256  = (N_EDGE + 255) / 256;         // 3125
    const int I256  = (N_ITEMS + 255) / 256;        // 3516

    // ---- sort (edges + self-loops) by dst ----
    init_hist_kernel<<<BIN_BLOCKS, 256, 0, stream>>>(hist);
    hist_kernel<<<E256, 256, 0, stream>>>(ei, hist);
    bsum_kernel<<<BIN_BLOCKS, 256, 0, stream>>>(hist, bsum);
    scan_bsum_kernel<<<1, 512, 0, stream>>>(bsum);
    rowptr_kernel<<<BIN_BLOCKS, 256, 0, stream>>>(hist, bsum, woff);
    scatter_edges_kernel<<<I256, 256, 0, stream>>>(ei, woff, srcS, dstS);

    // ---- weight prep + projection + output inits ----
    cvt_w1<<<(64 * 32 + 255) / 256, 256, 0, stream>>>(w1_1, w1t1, 7, 32, 64);
    cvt_w1<<<(128 * 96 + 255) / 256, 256, 0, stream>>>(w1_2, w1t2, 67, 96, 128);
    cvt_w1<<<(256 * 160 + 255) / 256, 256, 0, stream>>>(w1_3, w1t3, 131, 160, 256);
    cvt_w2<<<(64 * 64 + 255) / 256, 256, 0, stream>>>(w2_1, w2t1, 64);
    cvt_w2<<<(128 * 128 + 255) / 256, 256, 0, stream>>>(w2_2, w2t2, 128);
    cvt_w2<<<(256 * 256 + 255) / 256, 256, 0, stream>>>(w2_3, w2t3, 256);
    proj_kernel<<<(N_PTS + 255) / 256, 256, 0, stream>>>(pos, proj, img_h, img_w, pix);
    init_out_kernel<<<(N_PTS * 64 / 4 + 255) / 256, 256, 0, stream>>>(F0, (long)N_PTS * 64);
    init_out_kernel<<<(N_PTS * 128 / 4 + 255) / 256, 256, 0, stream>>>(F1, (long)N_PTS * 128);

    // layer 1 (din 4 -> 64)
    node_mfma_kernel<4, 32, 64><<<NODE_BLOCKS, 256, 0, stream>>>(x, pos, w1t1, b1_1, A12);
    gemm_msg_kernel<64><<<EDGE_P_BLOCKS, 256, 0, stream>>>(srcS, dstS, A12, pos, w1_1 + 4 * 64, w2t1, b2_1, F0, N_ITEMS);

    // layer 2 (64 -> 128)
    node_mfma_kernel<64, 96, 128><<<NODE_BLOCKS, 256, 0, stream>>>(F0, pos, w1t2, b1_2, A12);
    gemm_msg_kernel<128><<<EDGE_P_BLOCKS, 256, 0, stream>>>(srcS, dstS, A12, pos, w1_2 + 64 * 128, w2t2, b2_2, F1, N_ITEMS);

    // layer 3 (128 -> 256) — persistent r10-structure kernel
    node_mfma_kernel<128, 160, 256><<<NODE_BLOCKS, 256, 0, stream>>>(F1, pos, w1t3, b1_3, A3);
    init_out_kernel<<<(N_PTS * 256 / 4 + 255) / 256, 256, 0, stream>>>(HH, (long)N_PTS * 256);
    gemm_msg256_kernel<<<EDGE_P_BLOCKS, 256, 0, stream>>>(srcS, dstS, A3, pos, w1_3 + 128 * 256, w2t3, b2_3, HH, N_ITEMS);

    // scatter + pool in 32-channel chunks (img aliases A3 — after edge3 only)
    for (int cb = 0; cb < 256; cb += CHUNK) {
        hipMemsetAsync(img, 0, (size_t)IMG_W * IMG_H * CHUNK * 4, stream);
        scatter_kernel<<<(N_PTS * CHUNK) / 256, 256, 0, stream>>>(HH, pix, img, cb);
        pool_kernel<<<OW * OH, CHUNK, 0, stream>>>(img, out, cb);
    }
}

// Round 17
// 1571.414 us; speedup vs baseline: 1.0918x; 1.0918x over previous
//
#include <hip/hip_runtime.h>
#include <cstdint>

#define N_PTS 100000
#define N_EDGE 800000
#define N_ITEMS (N_EDGE + N_PTS)   // real edges + self-loops
#define IMG_W 1216
#define IMG_H 240
#define OW 304
#define OH 60
#define CHUNK 32
#define BIN_BLOCKS 391   // ceil(N_PTS/256)

typedef _Float16 f16;
typedef _Float16 f16x8 __attribute__((ext_vector_type(8)));
typedef float f32x4 __attribute__((ext_vector_type(4)));

__device__ __forceinline__ void atomicMaxF(float* addr, float v) {
    // float max via int max (v>=0) / uint min (v<0); exact, order-independent.
    if (v >= 0.0f) atomicMax((int*)addr, __float_as_int(v));
    else atomicMin((unsigned int*)addr, __float_as_uint(v));
}

// ---------------- init OUT to -inf ----------------
__global__ __launch_bounds__(256)
void init_out_kernel(float* __restrict__ p, long n)   // n multiple of 4
{
    long i = ((long)blockIdx.x * 256 + threadIdx.x) * 4;
    if (i < n) {
        float4 v = {-INFINITY, -INFINITY, -INFINITY, -INFINITY};
        *(float4*)&p[i] = v;
    }
}

// ---------------- MFMA node kernel: A[n] = [X|pos]@w1 + b1 (f16) ----------------
template<int DX, int KP, int D>
__global__ __launch_bounds__(256)
void node_mfma_kernel(const float* __restrict__ X, const float* __restrict__ pos,
                      const f16* __restrict__ w1t, const float* __restrict__ b1,
                      f16* __restrict__ A)
{
    constexpr int KB = KP / 32;
    constexpr int NB = D / 16;
    const int tid = threadIdx.x;
    const int wave = tid >> 6;
    const int lane = tid & 63;
    const int row = lane & 15;
    const int kg = lane >> 4;
    const int wbase = (blockIdx.x * 4 + wave) * 32;

    f16x8 pa[2][KB];
#pragma unroll
    for (int mh = 0; mh < 2; ++mh) {
        int n = wbase + mh * 16 + row;
        int ns = (n < N_PTS) ? n : 0;
#pragma unroll
        for (int kb = 0; kb < KB; ++kb) {
            const int c0 = kb * 32 + kg * 8;
            f16x8 h;
#pragma unroll
            for (int j = 0; j < 8; ++j) {
                int k = c0 + j;
                float v = 0.0f;
                if (k < DX) v = X[(long)ns * DX + k];
                else if (k < DX + 3) v = pos[(long)ns * 3 + (k - DX)];
                h[j] = (f16)v;
            }
            pa[mh][kb] = h;
        }
    }

#pragma unroll 2
    for (int nb = 0; nb < NB; ++nb) {
        f32x4 acc0 = {0.0f, 0.0f, 0.0f, 0.0f};
        f32x4 acc1 = {0.0f, 0.0f, 0.0f, 0.0f};
#pragma unroll
        for (int kb = 0; kb < KB; ++kb) {
            f16x8 pb = *(const f16x8*)&w1t[(long)(nb * 16 + row) * KP + kb * 32 + kg * 8];
            acc0 = __builtin_amdgcn_mfma_f32_16x16x32_f16(pa[0][kb], pb, acc0, 0, 0, 0);
            acc1 = __builtin_amdgcn_mfma_f32_16x16x32_f16(pa[1][kb], pb, acc1, 0, 0, 0);
        }
        const int col = nb * 16 + row;
        const float bb = b1[col];
#pragma unroll
        for (int reg = 0; reg < 4; ++reg) {
            int r = kg * 4 + reg;
            int n0 = wbase + r;
            int n1 = wbase + 16 + r;
            if (n0 < N_PTS) A[(long)n0 * D + col] = (f16)(acc0[reg] + bb);
            if (n1 < N_PTS) A[(long)n1 * D + col] = (f16)(acc1[reg] + bb);
        }
    }
}

// ---------------- weight prep ----------------
__global__ void cvt_w1(const float* __restrict__ w1, f16* __restrict__ w1t,
                       int K, int KP, int D)
{
    int i = blockIdx.x * 256 + threadIdx.x;
    if (i >= D * KP) return;
    int c = i / KP, k = i % KP;
    w1t[i] = (k < K) ? (f16)w1[k * D + c] : (f16)0.0f;
}

__global__ void cvt_w2(const float* __restrict__ w2, f16* __restrict__ w2t, int D)
{
    int i = blockIdx.x * 256 + threadIdx.x;
    if (i >= D * D) return;
    int n = i / D, k = i % D;
    w2t[i] = (f16)w2[k * D + n];
}

// ---------------- counting sort of (edges + self-loops) by dst ----------------
__global__ void init_hist_kernel(int* __restrict__ hist)
{
    int i = blockIdx.x * 256 + threadIdx.x;
    if (i < N_PTS) hist[i] = 1;   // self-loop
}

__global__ void hist_kernel(const int* __restrict__ ei, int* __restrict__ hist)
{
    int e = blockIdx.x * 256 + threadIdx.x;
    if (e < N_EDGE) atomicAdd(&hist[ei[N_EDGE + e]], 1);
}

__global__ void bsum_kernel(const int* __restrict__ hist, int* __restrict__ bsum)
{
    __shared__ int s[256];
    int i = blockIdx.x * 256 + threadIdx.x;
    s[threadIdx.x] = (i < N_PTS) ? hist[i] : 0;
    __syncthreads();
    for (int off = 128; off > 0; off >>= 1) {
        if (threadIdx.x < off) s[threadIdx.x] += s[threadIdx.x + off];
        __syncthreads();
    }
    if (threadIdx.x == 0) bsum[blockIdx.x] = s[0];
}

__global__ void scan_bsum_kernel(int* __restrict__ bsum)
{
    __shared__ int s[512];
    int t = threadIdx.x;
    int v = (t < BIN_BLOCKS) ? bsum[t] : 0;
    s[t] = v;
    __syncthreads();
    for (int off = 1; off < 512; off <<= 1) {
        int u = (t >= off) ? s[t - off] : 0;
        __syncthreads();
        s[t] += u;
        __syncthreads();
    }
    if (t < BIN_BLOCKS) bsum[t] = s[t] - v;   // exclusive
}

__global__ void rowptr_kernel(const int* __restrict__ hist, const int* __restrict__ bsum,
                              int* __restrict__ woff)
{
    __shared__ int s[256];
    int i = blockIdx.x * 256 + threadIdx.x;
    int v = (i < N_PTS) ? hist[i] : 0;
    s[threadIdx.x] = v;
    __syncthreads();
    for (int off = 1; off < 256; off <<= 1) {
        int u = (threadIdx.x >= off) ? s[threadIdx.x - off] : 0;
        __syncthreads();
        s[threadIdx.x] += u;
        __syncthreads();
    }
    if (i < N_PTS) woff[i] = bsum[blockIdx.x] + s[threadIdx.x] - v;  // exclusive
}

__global__ void scatter_edges_kernel(const int* __restrict__ ei, int* __restrict__ woff,
                                     int* __restrict__ srcS, int* __restrict__ dstS)
{
    int e = blockIdx.x * 256 + threadIdx.x;
    if (e >= N_ITEMS) return;
    int s, d;
    if (e < N_EDGE) { s = ei[e]; d = ei[N_EDGE + e]; }
    else            { s = d = e - N_EDGE; }
    int p = atomicAdd(&woff[d], 1);
    srcS[p] = s;
    dstS[p] = d;
}

// ---------------- 1-wave 32-item MFMA message kernel (XKG dedup) D=64/128 -----------
template<int D>
__global__ __launch_bounds__(64)
void gemm_msg_kernel(const int* __restrict__ srcA, const int* __restrict__ dstA,
                     const f16* __restrict__ A, const float* __restrict__ pos,
                     const float* __restrict__ w1p, const f16* __restrict__ w2t,
                     const float* __restrict__ b2, float* __restrict__ OUT, int nItems)
{
    constexpr int KB = D / 32;
    constexpr int NB = D / 16;
    const int lane = threadIdx.x & 63;
    const int row = lane & 15;
    const int kg = lane >> 4;
    const long wbase = (long)blockIdx.x * 32;

    int s[2], d[2];
    float px[2], py[2], pz[2];
#pragma unroll
    for (int mh = 0; mh < 2; ++mh) {
        long e = wbase + mh * 16 + row;
        bool ok = (e < nItems);
        int ss = ok ? srcA[e] : 0;
        int dd = ok ? dstA[e] : -1;
        s[mh] = ss; d[mh] = dd;
        int dsafe = ok ? dd : 0;
        px[mh] = pos[(long)dsafe * 3 + 0];
        py[mh] = pos[(long)dsafe * 3 + 1];
        pz[mh] = pos[(long)dsafe * 3 + 2];
    }

    f16x8 pa[2][KB];
#pragma unroll
    for (int kb = 0; kb < KB; ++kb) {
        const int c0 = kb * 32 + kg * 8;
        f16x8 a0 = *(const f16x8*)&A[(long)s[0] * D + c0];
        f16x8 a1 = *(const f16x8*)&A[(long)s[1] * D + c0];
        f16x8 h0, h1;
#pragma unroll
        for (int j = 0; j < 8; ++j) {
            float wx = w1p[c0 + j];
            float wy = w1p[D + c0 + j];
            float wz = w1p[2 * D + c0 + j];
            h0[j] = (f16)fmaxf((float)a0[j] - (px[0] * wx + py[0] * wy + pz[0] * wz), 0.0f);
            h1[j] = (f16)fmaxf((float)a1[j] - (px[1] * wx + py[1] * wy + pz[1] * wz), 0.0f);
        }
        pa[0][kb] = h0;
        pa[1][kb] = h1;
    }

    int dd0[4], dd1[4];
#pragma unroll
    for (int reg = 0; reg < 4; ++reg) {
        int r = kg * 4 + reg;
        dd0[reg] = __shfl(d[0], r);
        dd1[reg] = __shfl(d[1], r);
    }
    const bool a01 = (dd0[1] == dd0[0]), a12 = (dd0[2] == dd0[1]), a23 = (dd0[3] == dd0[2]);
    const bool b01 = (dd1[1] == dd1[0]), b12 = (dd1[2] == dd1[1]), b23 = (dd1[3] == dd1[2]);
    const bool aAll = a01 && a12 && a23, bAll = b01 && b12 && b23;
    const int aN0 = __shfl(dd0[0], lane + 16);
    const int bN0 = __shfl(dd1[0], lane + 16);
    const int aFn = __shfl((int)aAll, lane + 16);
    const int bFn = __shfl((int)bAll, lane + 16);
    const bool aCo = (kg < 3) && (dd0[3] == aN0);
    const bool bCo = (kg < 3) && (dd1[3] == bN0);
    const int lprev = (lane >= 16) ? (lane - 16) : 0;
    const int aP3 = __shfl(dd0[3], lprev);
    const int bP3 = __shfl(dd1[3], lprev);
    const bool aHd = (kg == 0) || (dd0[0] != aP3);
    const bool bHd = (kg == 0) || (dd1[0] != bP3);

#pragma unroll
    for (int nb = 0; nb < NB; ++nb) {
        f32x4 acc0 = {0.0f, 0.0f, 0.0f, 0.0f};
        f32x4 acc1 = {0.0f, 0.0f, 0.0f, 0.0f};
#pragma unroll
        for (int kb = 0; kb < KB; ++kb) {
            f16x8 pb = *(const f16x8*)&w2t[(long)(nb * 16 + row) * D + kb * 32 + kg * 8];
            acc0 = __builtin_amdgcn_mfma_f32_16x16x32_f16(pa[0][kb], pb, acc0, 0, 0, 0);
            acc1 = __builtin_amdgcn_mfma_f32_16x16x32_f16(pa[1][kb], pb, acc1, 0, 0, 0);
        }
        const int col = nb * 16 + row;
        const float bb = b2[col];
        {   // half 0
            const float v0 = acc0[0] + bb, v1 = acc0[1] + bb, v2 = acc0[2] + bb, v3 = acc0[3] + bb;
            const float s3 = v3;
            const float s2 = a23 ? fmaxf(v2, s3) : v2;
            const float s1 = a12 ? fmaxf(v1, s2) : v1;
            const float s0 = a01 ? fmaxf(v0, s1) : v0;
            float P = v0;
            P = a01 ? fmaxf(P, v1) : P;
            P = (a01 && a12) ? fmaxf(P, v2) : P;
            P = aAll ? fmaxf(P, v3) : P;
            float T = -INFINITY;
#pragma unroll
            for (int it = 0; it < 3; ++it) {
                float Pn = __shfl(P, lane + 16);
                float Tn = __shfl(T, lane + 16);
                T = aCo ? fmaxf(Pn, aFn ? Tn : -INFINITY) : T;
            }
            const float x0 = aAll ? fmaxf(s0, T) : s0;
            const float x1 = (a12 && a23) ? fmaxf(s1, T) : s1;
            const float x2 = a23 ? fmaxf(s2, T) : s2;
            const float x3 = fmaxf(s3, T);
            if (aHd  && dd0[0] >= 0) atomicMaxF(&OUT[(long)dd0[0] * D + col], x0);
            if (!a01 && dd0[1] >= 0) atomicMaxF(&OUT[(long)dd0[1] * D + col], x1);
            if (!a12 && dd0[2] >= 0) atomicMaxF(&OUT[(long)dd0[2] * D + col], x2);
            if (!a23 && dd0[3] >= 0) atomicMaxF(&OUT[(long)dd0[3] * D + col], x3);
        }
        {   // half 1
            const float v0 = acc1[0] + bb, v1 = acc1[1] + bb, v2 = acc1[2] + bb, v3 = acc1[3] + bb;
            const float s3 = v3;
            const float s2 = b23 ? fmaxf(v2, s3) : v2;
            const float s1 = b12 ? fmaxf(v1, s2) : v1;
            const float s0 = b01 ? fmaxf(v0, s1) : v0;
            float P = v0;
            P = b01 ? fmaxf(P, v1) : P;
            P = (b01 && b12) ? fmaxf(P, v2) : P;
            P = bAll ? fmaxf(P, v3) : P;
            float T = -INFINITY;
#pragma unroll
            for (int it = 0; it < 3; ++it) {
                float Pn = __shfl(P, lane + 16);
                float Tn = __shfl(T, lane + 16);
                T = bCo ? fmaxf(Pn, bFn ? Tn : -INFINITY) : T;
            }
            const float x0 = bAll ? fmaxf(s0, T) : s0;
            const float x1 = (b12 && b23) ? fmaxf(s1, T) : s1;
            const float x2 = b23 ? fmaxf(s2, T) : s2;
            const float x3 = fmaxf(s3, T);
            if (bHd  && dd1[0] >= 0) atomicMaxF(&OUT[(long)dd1[0] * D + col], x0);
            if (!b01 && dd1[1] >= 0) atomicMaxF(&OUT[(long)dd1[1] * D + col], x1);
            if (!b12 && dd1[2] >= 0) atomicMaxF(&OUT[(long)dd1[2] * D + col], x2);
            if (!b23 && dd1[3] >= 0) atomicMaxF(&OUT[(long)dd1[3] * D + col], x3);
        }
    }
}

// ---------------- 1-wave standalone D=256 kernel (per-lane dedup, r10 body) ---------
__global__ __launch_bounds__(64)
void gemm_msg256_kernel(const int* __restrict__ srcA, const int* __restrict__ dstA,
                        const f16* __restrict__ A, const float* __restrict__ pos,
                        const float* __restrict__ w1p, const f16* __restrict__ w2t,
                        const float* __restrict__ b2, float* __restrict__ OUT, int nItems)
{
    const int lane = threadIdx.x & 63;
    const int row = lane & 15;
    const int kg = lane >> 4;
    const long wbase = (long)blockIdx.x * 32;

    int s[2], d[2];
    float px[2], py[2], pz[2];
#pragma unroll
    for (int mh = 0; mh < 2; ++mh) {
        long e = wbase + mh * 16 + row;
        bool ok = (e < nItems);
        int ss = ok ? srcA[e] : 0;
        int dd = ok ? dstA[e] : -1;
        s[mh] = ss; d[mh] = dd;
        int dsafe = ok ? dd : 0;
        px[mh] = pos[(long)dsafe * 3 + 0];
        py[mh] = pos[(long)dsafe * 3 + 1];
        pz[mh] = pos[(long)dsafe * 3 + 2];
    }

    f16x8 pa[2][8];
#pragma unroll
    for (int kb = 0; kb < 8; ++kb) {
        const int c0 = kb * 32 + kg * 8;
        f16x8 a0 = *(const f16x8*)&A[(long)s[0] * 256 + c0];
        f16x8 a1 = *(const f16x8*)&A[(long)s[1] * 256 + c0];
        f16x8 h0, h1;
#pragma unroll
        for (int j = 0; j < 8; ++j) {
            float wx = w1p[c0 + j];
            float wy = w1p[256 + c0 + j];
            float wz = w1p[512 + c0 + j];
            h0[j] = (f16)fmaxf((float)a0[j] - (px[0] * wx + py[0] * wy + pz[0] * wz), 0.0f);
            h1[j] = (f16)fmaxf((float)a1[j] - (px[1] * wx + py[1] * wy + pz[1] * wz), 0.0f);
        }
        pa[0][kb] = h0;
        pa[1][kb] = h1;
    }

    int dd0[4], dd1[4];
#pragma unroll
    for (int reg = 0; reg < 4; ++reg) {
        int r = kg * 4 + reg;
        dd0[reg] = __shfl(d[0], r);
        dd1[reg] = __shfl(d[1], r);
    }
    bool hd0[4], hd1[4];
    hd0[0] = true; hd1[0] = true;
#pragma unroll
    for (int reg = 1; reg < 4; ++reg) {
        hd0[reg] = (dd0[reg] != dd0[reg - 1]);
        hd1[reg] = (dd1[reg] != dd1[reg - 1]);
    }

#pragma unroll
    for (int nb = 0; nb < 16; ++nb) {
        f32x4 acc0 = {0.0f, 0.0f, 0.0f, 0.0f};
        f32x4 acc1 = {0.0f, 0.0f, 0.0f, 0.0f};
#pragma unroll
        for (int kb = 0; kb < 8; ++kb) {
            f16x8 pb = *(const f16x8*)&w2t[(long)(nb * 16 + row) * 256 + kb * 32 + kg * 8];
            acc0 = __builtin_amdgcn_mfma_f32_16x16x32_f16(pa[0][kb], pb, acc0, 0, 0, 0);
            acc1 = __builtin_amdgcn_mfma_f32_16x16x32_f16(pa[1][kb], pb, acc1, 0, 0, 0);
        }
        const int col = nb * 16 + row;
        const float bb = b2[col];
        float v0[4], v1[4];
#pragma unroll
        for (int reg = 0; reg < 4; ++reg) { v0[reg] = acc0[reg] + bb; v1[reg] = acc1[reg] + bb; }
        float s0[4], s1[4];
        s0[3] = v0[3]; s1[3] = v1[3];
#pragma unroll
        for (int reg = 2; reg >= 0; --reg) {
            s0[reg] = hd0[reg + 1] ? v0[reg] : fmaxf(v0[reg], s0[reg + 1]);
            s1[reg] = hd1[reg + 1] ? v1[reg] : fmaxf(v1[reg], s1[reg + 1]);
        }
#pragma unroll
        for (int reg = 0; reg < 4; ++reg) {
            if (hd0[reg] && dd0[reg] >= 0) atomicMaxF(&OUT[(long)dd0[reg] * 256 + col], s0[reg]);
            if (hd1[reg] && dd1[reg] >= 0) atomicMaxF(&OUT[(long)dd1[reg] * 256 + col], s1[reg]);
        }
    }
}

// ---------------- projection ----------------
__global__ void proj_kernel(const float* __restrict__ pos, const float* __restrict__ proj,
                            const int* __restrict__ img_h, const int* __restrict__ img_w,
                            int* __restrict__ pix)
{
    int n = blockIdx.x * blockDim.x + threadIdx.x;
    if (n >= N_PTS) return;
    float px = pos[n * 3 + 0], py = pos[n * 3 + 1], pz = pos[n * 3 + 2];
    float h0 = proj[0] * px + proj[1] * py + proj[2]  * pz + proj[3];
    float h1 = proj[4] * px + proj[5] * py + proj[6]  * pz + proj[7];
    float h2 = proj[8] * px + proj[9] * py + proj[10] * pz + proj[11];
    int off_u = img_w[0] - IMG_W;
    int off_v = img_h[0] - IMG_H;
    int ui = (int)(short)(h0 / h2) - off_u;   // int16 truncation semantics
    int vi = (int)(short)(h1 / h2) - off_v;
    bool valid = (ui >= 0) && (vi >= 0) && (ui < IMG_W) && (vi < IMG_H);
    pix[n] = valid ? (ui * IMG_H + vi) : -1;
}

// ---------------- scatter-add (pixel-major, CHUNK channels) ----------------
__global__ __launch_bounds__(256)
void scatter_kernel(const float* __restrict__ H, const int* __restrict__ pix,
                    float* __restrict__ img, int cbase)
{
    long g = (long)blockIdx.x * blockDim.x + threadIdx.x;
    if (g >= (long)N_PTS * CHUNK) return;
    int n = (int)(g / CHUNK);
    int c = (int)(g % CHUNK);
    int p = pix[n];
    if (p < 0) return;
    atomicAdd(&img[(long)p * CHUNK + c], H[(long)n * 256 + cbase + c]);
}

// ---------------- 4x4 max-pool ----------------
__global__ __launch_bounds__(CHUNK)
void pool_kernel(const float* __restrict__ img, float* __restrict__ out, int cbase)
{
    int cell = blockIdx.x;
    int wc = cell / OH, hc = cell % OH;
    int c = threadIdx.x;
    float mx = -INFINITY;
#pragma unroll
    for (int i = 0; i < 4; ++i)
#pragma unroll
        for (int j = 0; j < 4; ++j) {
            long p = (long)(wc * 4 + i) * IMG_H + (hc * 4 + j);
            mx = fmaxf(mx, img[p * CHUNK + c]);
        }
    out[(long)(cbase + c) * (OW * OH) + wc * OH + hc] = mx;
}

extern "C" void kernel_launch(void* const* d_in, const int* in_sizes, int n_in,
                              void* d_out, int out_size, void* d_ws, size_t ws_size,
                              hipStream_t stream)
{
    const float* x     = (const float*)d_in[0];
    const float* pos   = (const float*)d_in[1];
    const int*   ei    = (const int*)d_in[2];
    const float* proj  = (const float*)d_in[4];
    const int*   img_h = (const int*)d_in[5];
    const int*   img_w = (const int*)d_in[6];
    const float* w1_1 = (const float*)d_in[7];
    const float* b1_1 = (const float*)d_in[8];
    const float* w2_1 = (const float*)d_in[9];
    const float* b2_1 = (const float*)d_in[10];
    const float* w1_2 = (const float*)d_in[11];
    const float* b1_2 = (const float*)d_in[12];
    const float* w2_2 = (const float*)d_in[13];
    const float* b2_2 = (const float*)d_in[14];
    const float* w1_3 = (const float*)d_in[15];
    const float* b1_3 = (const float*)d_in[16];
    const float* w2_3 = (const float*)d_in[17];
    const float* b2_3 = (const float*)d_in[18];
    float* out = (float*)d_out;

    // ws layout (byte offsets), lifetime-aliased; peak = 162.4 MB (proven rounds 6-16)
    if (ws_size < 162400000ull) return;
    char* ws = (char*)d_ws;
    float* HH   = (float*)(ws + 0);
    float* F1   = (float*)(ws + 0);
    float* F0   = (float*)(ws + 51200000);
    f16*   A12  = (f16*)(ws + 76800000);
    f16*   A3   = (f16*)(ws + 102400000);
    float* img  = (float*)(ws + 102400000);
    int*   pix  = (int*)(ws + 153600000);
    f16*   w2t3 = (f16*)(ws + 154000000);
    f16*   w2t2 = (f16*)(ws + 154131072);
    f16*   w2t1 = (f16*)(ws + 154163840);
    int*   srcS = (int*)(ws + 154200000);
    int*   dstS = (int*)(ws + 157800000);
    int*   hist = (int*)(ws + 161400000);
    int*   woff = (int*)(ws + 161800000);
    int*   bsum = (int*)(ws + 162200000);
    f16*   w1t3 = (f16*)(ws + 162210000);
    f16*   w1t2 = (f16*)(ws + 162300000);
    f16*   w1t1 = (f16*)(ws + 162330000);

    const int NODE_BLOCKS = (N_PTS + 127) / 128;    // 782 (4 waves x 32 rows)
    const int WIN_BLOCKS  = (N_ITEMS + 31) / 32;    // 28125 (1 wave x 32 items)
    const int E256  = (N_EDGE + 255) / 256;         // 3125
    const int I256  = (N_ITEMS + 255) / 256;        // 3516

    // ---- sort (edges + self-loops) by dst ----
    init_hist_kernel<<<BIN_BLOCKS, 256, 0, stream>>>(hist);
    hist_kernel<<<E256, 256, 0, stream>>>(ei, hist);
    bsum_kernel<<<BIN_BLOCKS, 256, 0, stream>>>(hist, bsum);
    scan_bsum_kernel<<<1, 512, 0, stream>>>(bsum);
    rowptr_kernel<<<BIN_BLOCKS, 256, 0, stream>>>(hist, bsum, woff);
    scatter_edges_kernel<<<I256, 256, 0, stream>>>(ei, woff, srcS, dstS);

    // ---- weight prep + projection + output inits ----
    cvt_w1<<<(64 * 32 + 255) / 256, 256, 0, stream>>>(w1_1, w1t1, 7, 32, 64);
    cvt_w1<<<(128 * 96 + 255) / 256, 256, 0, stream>>>(w1_2, w1t2, 67, 96, 128);
    cvt_w1<<<(256 * 160 + 255) / 256, 256, 0, stream>>>(w1_3, w1t3, 131, 160, 256);
    cvt_w2<<<(64 * 64 + 255) / 256, 256, 0, stream>>>(w2_1, w2t1, 64);
    cvt_w2<<<(128 * 128 + 255) / 256, 256, 0, stream>>>(w2_2, w2t2, 128);
    cvt_w2<<<(256 * 256 + 255) / 256, 256, 0, stream>>>(w2_3, w2t3, 256);
    proj_kernel<<<(N_PTS + 255) / 256, 256, 0, stream>>>(pos, proj, img_h, img_w, pix);
    init_out_kernel<<<(N_PTS * 64 / 4 + 255) / 256, 256, 0, stream>>>(F0, (long)N_PTS * 64);
    init_out_kernel<<<(N_PTS * 128 / 4 + 255) / 256, 256, 0, stream>>>(F1, (long)N_PTS * 128);

    // layer 1 (din 4 -> 64)
    node_mfma_kernel<4, 32, 64><<<NODE_BLOCKS, 256, 0, stream>>>(x, pos, w1t1, b1_1, A12);
    gemm_msg_kernel<64><<<WIN_BLOCKS, 64, 0, stream>>>(srcS, dstS, A12, pos, w1_1 + 4 * 64, w2t1, b2_1, F0, N_ITEMS);

    // layer 2 (64 -> 128)
    node_mfma_kernel<64, 96, 128><<<NODE_BLOCKS, 256, 0, stream>>>(F0, pos, w1t2, b1_2, A12);
    gemm_msg_kernel<128><<<WIN_BLOCKS, 64, 0, stream>>>(srcS, dstS, A12, pos, w1_2 + 64 * 128, w2t2, b2_2, F1, N_ITEMS);

    // layer 3 (128 -> 256) — 1-wave blocks, r10 body
    node_mfma_kernel<128, 160, 256><<<NODE_BLOCKS, 256, 0, stream>>>(F1, pos, w1t3, b1_3, A3);
    init_out_kernel<<<(N_PTS * 256 / 4 + 255) / 256, 256, 0, stream>>>(HH, (long)N_PTS * 256);
    gemm_msg256_kernel<<<WIN_BLOCKS, 64, 0, stream>>>(srcS, dstS, A3, pos, w1_3 + 128 * 256, w2t3, b2_3, HH, N_ITEMS);

    // scatter + pool in 32-channel chunks (img aliases A3 — after edge3 only)
    for (int cb = 0; cb < 256; cb += CHUNK) {
        hipMemsetAsync(img, 0, (size_t)IMG_W * IMG_H * CHUNK * 4, stream);
        scatter_kernel<<<(N_PTS * CHUNK) / 256, 256, 0, stream>>>(HH, pix, img, cb);
        pool_kernel<<<OW * OH, CHUNK, 0, stream>>>(img, out, cb);
    }
}